// Round 5
// baseline (1454.798 us; speedup 1.0000x reference)
//
#include <hip/hip_runtime.h>

// 2-layer LSTM (H=64, D=1), N=2048, T=512 — MFMA bf16 3-term split precision.
// R5: dual-group ILP. Block = 32 samples = 2 groups(A,B) x 16, 4 waves,
// grid = 64 blocks. Per barrier interval each wave runs TWO independent
// streams (A and B) -> latency hiding at 1 wave/SIMD. Outputs buffered in
// LDS, flushed every 64 steps (kills per-step vmcnt(0) drain at barriers).
// Weights (hi+lo, 192 regs/lane) in unified VGPR/AGPR file; identical
// fragments serve both groups.

typedef __attribute__((ext_vector_type(8))) short short8;
typedef __attribute__((ext_vector_type(4))) float f32x4;

#define XPITCH 2060                 // bytes; 515 words (odd) -> conflict-free x reads
#define XP 0                        // 32 * 2060 = 65920
#define HP 65920                    // 16 planes * 2304 = 36864
#define OPB_ 102784                 // 2 * 64*4*16*4 = 32768
#define LDS_BYTES 135552

// plane(buf, grp, layer, hilo): 2304 B each, [16 s][144 B of bf16 k-row data]
#define PLANE(buf, grp, layer, hl) (HP + (((buf) * 8) + (grp) * 4 + (layer) * 2 + (hl)) * 2304)

__device__ __forceinline__ float fast_rcp(float x) { return __builtin_amdgcn_rcpf(x); }
__device__ __forceinline__ float sigm(float x) { return fast_rcp(1.0f + __expf(-x)); }
// tanh(x) = 2/(1+exp(-2x)) - 1 : no clamp needed, saturates via inf->rcp->0
__device__ __forceinline__ float tanh2(float x) {
  const float e = __expf(-2.0f * x);
  return fmaf(2.0f, fast_rcp(1.0f + e), -1.0f);
}
__device__ __forceinline__ unsigned short bf_rne(float f) {
  unsigned u = __float_as_uint(f);
  return (unsigned short)((u + 0x7FFFu + ((u >> 16) & 1u)) >> 16);
}
__device__ __forceinline__ void split8(const float* p, short8& hi, short8& lo) {
#pragma unroll
  for (int e = 0; e < 8; ++e) {
    float v = p[e];
    unsigned short h = bf_rne(v);
    float hf = __uint_as_float(((unsigned)h) << 16);
    hi[e] = (short)h;
    lo[e] = (short)bf_rne(v - hf);
  }
}
__device__ __forceinline__ unsigned cvt_pk(float a, float b) {
  unsigned r;
  asm("v_cvt_pk_bf16_f32 %0, %1, %2" : "=v"(r) : "v"(a), "v"(b));
  return r;
}
__device__ __forceinline__ f32x4 mfma16(short8 a, short8 b, f32x4 c) {
  return __builtin_amdgcn_mfma_f32_16x16x32_bf16(a, b, c, 0, 0, 0);
}

__global__ __launch_bounds__(256, 1) void lstm2_mfma(
    const float* __restrict__ y, const float* __restrict__ Wih1,
    const float* __restrict__ Whh1, const float* __restrict__ bih1,
    const float* __restrict__ bhh1, const float* __restrict__ Wih2,
    const float* __restrict__ Whh2, const float* __restrict__ bih2,
    const float* __restrict__ bhh2, const float* __restrict__ Wlin,
    const float* __restrict__ blin, float* __restrict__ out) {
  extern __shared__ char smem[];
  const int tid = threadIdx.x;
  const int w = tid >> 6;          // wave 0..3
  const int lane = tid & 63;
  const int g = lane >> 4;         // k-group 0..3
  const int s = lane & 15;         // sample col AND A row-within-tile
  const int s0 = blockIdx.x * 32;

  // ---- stage x for 32 samples: XP[ss][t] ----
  for (int i = tid; i < 32 * 512; i += 256) {
    const int ss = i >> 9, t = i & 511;
    *(float*)(smem + XP + ss * XPITCH + t * 4) = y[(size_t)(s0 + ss) * 512 + t];
  }
  // ---- zero all h planes ----
  for (int i = tid; i < 36864 / 4; i += 256) *(float*)(smem + HP + i * 4) = 0.f;

  // ---- weight fragments (hi+lo register/AGPR-resident; shared by A and B) ----
  short8 a1h[4][2], a1l[4][2], a2h[4][4], a2l[4][4];
  {
    const int row = 16 * w + s;
#pragma unroll
    for (int p = 0; p < 4; ++p) {
#pragma unroll
      for (int c = 0; c < 2; ++c)
        split8(Whh1 + (size_t)(p * 64 + row) * 64 + 32 * c + 8 * g, a1h[p][c], a1l[p][c]);
#pragma unroll
      for (int c = 0; c < 4; ++c) {
        const float* src = (c < 2) ? (Wih2 + (size_t)(p * 64 + row) * 64 + 32 * c + 8 * g)
                                   : (Whh2 + (size_t)(p * 64 + row) * 64 + 32 * (c - 2) + 8 * g);
        split8(src, a2h[p][c], a2l[p][c]);
      }
    }
  }

  // ---- per-lane constants (D layout: row = 4g + r within tile) ----
  float bias1c[4][4], wih1c[4][4], bias2c[4][4], wlinc[4];
#pragma unroll
  for (int p = 0; p < 4; ++p)
#pragma unroll
    for (int r = 0; r < 4; ++r) {
      const int row = p * 64 + 16 * w + 4 * g + r;
      bias1c[p][r] = bih1[row] + bhh1[row];
      wih1c[p][r] = Wih1[row];
      bias2c[p][r] = bih2[row] + bhh2[row];
    }
#pragma unroll
  for (int r = 0; r < 4; ++r) wlinc[r] = Wlin[16 * w + 4 * g + r];
  const float bl0 = blin[0];

  float c1A[4] = {0, 0, 0, 0}, c2A[4] = {0, 0, 0, 0};
  float c1B[4] = {0, 0, 0, 0}, c2B[4] = {0, 0, 0, 0};
  __syncthreads();

#pragma unroll 1
  for (int n = 0; n < 512; ++n) {
    const int rb = n & 1, wb = rb ^ 1;
    const int boffc0 = s * 144 + 16 * g;
    const int hoff = s * 144 + 32 * w + 8 * g;
    const float xA = *(const float*)(smem + XP + s * XPITCH + n * 4);
    const float xB = *(const float*)(smem + XP + (s + 16) * XPITCH + n * 4);

    // ================= interval 1: layer 1 of A and B =================
    f32x4 aA[4], aB[4];
#pragma unroll
    for (int p = 0; p < 4; ++p)
#pragma unroll
      for (int r = 0; r < 4; ++r) {
        aA[p][r] = fmaf(wih1c[p][r], xA, bias1c[p][r]);
        aB[p][r] = fmaf(wih1c[p][r], xB, bias1c[p][r]);
      }
#pragma unroll
    for (int c = 0; c < 2; ++c) {
      const int boff = boffc0 + 64 * c;
      const short8 BhA = *(const short8*)(smem + PLANE(rb, 0, 0, 0) + boff);
      const short8 BlA = *(const short8*)(smem + PLANE(rb, 0, 0, 1) + boff);
      const short8 BhB = *(const short8*)(smem + PLANE(rb, 1, 0, 0) + boff);
      const short8 BlB = *(const short8*)(smem + PLANE(rb, 1, 0, 1) + boff);
#pragma unroll
      for (int p = 0; p < 4; ++p) aA[p] = mfma16(a1h[p][c], BhA, aA[p]);
#pragma unroll
      for (int p = 0; p < 4; ++p) aB[p] = mfma16(a1h[p][c], BhB, aB[p]);
#pragma unroll
      for (int p = 0; p < 4; ++p) aA[p] = mfma16(a1h[p][c], BlA, aA[p]);
#pragma unroll
      for (int p = 0; p < 4; ++p) aB[p] = mfma16(a1h[p][c], BlB, aB[p]);
#pragma unroll
      for (int p = 0; p < 4; ++p) aA[p] = mfma16(a1l[p][c], BhA, aA[p]);
#pragma unroll
      for (int p = 0; p < 4; ++p) aB[p] = mfma16(a1l[p][c], BhB, aB[p]);
    }

    float h1A[4], h1B[4];
#pragma unroll
    for (int r = 0; r < 4; ++r) {
      {
        const float ig = sigm(aA[0][r]), fg = sigm(aA[1][r]);
        const float gg = tanh2(aA[2][r]), og = sigm(aA[3][r]);
        c1A[r] = fmaf(fg, c1A[r], ig * gg);
        h1A[r] = og * tanh2(c1A[r]);
      }
      {
        const float ig = sigm(aB[0][r]), fg = sigm(aB[1][r]);
        const float gg = tanh2(aB[2][r]), og = sigm(aB[3][r]);
        c1B[r] = fmaf(fg, c1B[r], ig * gg);
        h1B[r] = og * tanh2(c1B[r]);
      }
    }
    {  // pack h1A, h1B -> write-buffer planes
      const unsigned hA0 = cvt_pk(h1A[0], h1A[1]), hA1 = cvt_pk(h1A[2], h1A[3]);
      const unsigned lA0 = cvt_pk(h1A[0] - __uint_as_float(hA0 << 16),
                                  h1A[1] - __uint_as_float(hA0 & 0xFFFF0000u)),
                     lA1 = cvt_pk(h1A[2] - __uint_as_float(hA1 << 16),
                                  h1A[3] - __uint_as_float(hA1 & 0xFFFF0000u));
      *(uint2*)(smem + PLANE(wb, 0, 0, 0) + hoff) = make_uint2(hA0, hA1);
      *(uint2*)(smem + PLANE(wb, 0, 0, 1) + hoff) = make_uint2(lA0, lA1);
      const unsigned hB0 = cvt_pk(h1B[0], h1B[1]), hB1 = cvt_pk(h1B[2], h1B[3]);
      const unsigned lB0 = cvt_pk(h1B[0] - __uint_as_float(hB0 << 16),
                                  h1B[1] - __uint_as_float(hB0 & 0xFFFF0000u)),
                     lB1 = cvt_pk(h1B[2] - __uint_as_float(hB1 << 16),
                                  h1B[3] - __uint_as_float(hB1 & 0xFFFF0000u));
      *(uint2*)(smem + PLANE(wb, 1, 0, 0) + hoff) = make_uint2(hB0, hB1);
      *(uint2*)(smem + PLANE(wb, 1, 0, 1) + hoff) = make_uint2(lB0, lB1);
    }
    __syncthreads();

    // ================= interval 2: layer 2 of A and B =================
    f32x4 bA[4], bB[4];
#pragma unroll
    for (int p = 0; p < 4; ++p)
#pragma unroll
      for (int r = 0; r < 4; ++r) { bA[p][r] = bias2c[p][r]; bB[p][r] = bias2c[p][r]; }
#pragma unroll
    for (int c = 0; c < 4; ++c) {
      const int lay = (c < 2) ? 0 : 1;   // h1-new vs h2-old
      const int buf = (c < 2) ? wb : rb;
      const int boff = boffc0 + 64 * (c & 1);
      const short8 BhA = *(const short8*)(smem + PLANE(buf, 0, lay, 0) + boff);
      const short8 BlA = *(const short8*)(smem + PLANE(buf, 0, lay, 1) + boff);
      const short8 BhB = *(const short8*)(smem + PLANE(buf, 1, lay, 0) + boff);
      const short8 BlB = *(const short8*)(smem + PLANE(buf, 1, lay, 1) + boff);
#pragma unroll
      for (int p = 0; p < 4; ++p) bA[p] = mfma16(a2h[p][c], BhA, bA[p]);
#pragma unroll
      for (int p = 0; p < 4; ++p) bB[p] = mfma16(a2h[p][c], BhB, bB[p]);
#pragma unroll
      for (int p = 0; p < 4; ++p) bA[p] = mfma16(a2h[p][c], BlA, bA[p]);
#pragma unroll
      for (int p = 0; p < 4; ++p) bB[p] = mfma16(a2h[p][c], BlB, bB[p]);
#pragma unroll
      for (int p = 0; p < 4; ++p) bA[p] = mfma16(a2l[p][c], BhA, bA[p]);
#pragma unroll
      for (int p = 0; p < 4; ++p) bB[p] = mfma16(a2l[p][c], BhB, bB[p]);
    }

    float h2A[4], h2B[4];
#pragma unroll
    for (int r = 0; r < 4; ++r) {
      {
        const float ig = sigm(bA[0][r]), fg = sigm(bA[1][r]);
        const float gg = tanh2(bA[2][r]), og = sigm(bA[3][r]);
        c2A[r] = fmaf(fg, c2A[r], ig * gg);
        h2A[r] = og * tanh2(c2A[r]);
      }
      {
        const float ig = sigm(bB[0][r]), fg = sigm(bB[1][r]);
        const float gg = tanh2(bB[2][r]), og = sigm(bB[3][r]);
        c2B[r] = fmaf(fg, c2B[r], ig * gg);
        h2B[r] = og * tanh2(c2B[r]);
      }
    }
    {  // pack h2A, h2B
      const unsigned hA0 = cvt_pk(h2A[0], h2A[1]), hA1 = cvt_pk(h2A[2], h2A[3]);
      const unsigned lA0 = cvt_pk(h2A[0] - __uint_as_float(hA0 << 16),
                                  h2A[1] - __uint_as_float(hA0 & 0xFFFF0000u)),
                     lA1 = cvt_pk(h2A[2] - __uint_as_float(hA1 << 16),
                                  h2A[3] - __uint_as_float(hA1 & 0xFFFF0000u));
      *(uint2*)(smem + PLANE(wb, 0, 1, 0) + hoff) = make_uint2(hA0, hA1);
      *(uint2*)(smem + PLANE(wb, 0, 1, 1) + hoff) = make_uint2(lA0, lA1);
      const unsigned hB0 = cvt_pk(h2B[0], h2B[1]), hB1 = cvt_pk(h2B[2], h2B[3]);
      const unsigned lB0 = cvt_pk(h2B[0] - __uint_as_float(hB0 << 16),
                                  h2B[1] - __uint_as_float(hB0 & 0xFFFF0000u)),
                     lB1 = cvt_pk(h2B[2] - __uint_as_float(hB1 << 16),
                                  h2B[3] - __uint_as_float(hB1 & 0xFFFF0000u));
      *(uint2*)(smem + PLANE(wb, 1, 1, 0) + hoff) = make_uint2(hB0, hB1);
      *(uint2*)(smem + PLANE(wb, 1, 1, 1) + hoff) = make_uint2(lB0, lB1);
    }

    // ---- out partials -> LDS ring (slot = n & 63), no global store here ----
    {
      float pA = wlinc[0] * h2A[0];
      pA = fmaf(wlinc[1], h2A[1], pA);
      pA = fmaf(wlinc[2], h2A[2], pA);
      pA = fmaf(wlinc[3], h2A[3], pA);
      float pB = wlinc[0] * h2B[0];
      pB = fmaf(wlinc[1], h2B[1], pB);
      pB = fmaf(wlinc[2], h2B[2], pB);
      pB = fmaf(wlinc[3], h2B[3], pB);
      pA += __shfl_xor(pA, 16, 64);
      pA += __shfl_xor(pA, 32, 64);
      pB += __shfl_xor(pB, 16, 64);
      pB += __shfl_xor(pB, 32, 64);
      const int slot = n & 63;
      if (g == 0) {
        *(float*)(smem + OPB_ + (slot * 64 + w * 16 + s) * 4) = pA;
        *(float*)(smem + OPB_ + 16384 + (slot * 64 + w * 16 + s) * 4) = pB;
      }
    }
    __syncthreads();

    // ---- flush 64 steps of outputs (1/64 steps pays the global-store cost) ----
    if ((n & 63) == 63) {
      const int cbase = n - 63;
      const int grp = tid >> 7, rr = tid & 127, ss2 = rr >> 3, q = rr & 7;
      const float* op = (const float*)(smem + OPB_ + grp * 16384);
      const size_t obase = (size_t)(s0 + grp * 16 + ss2) * 511;
#pragma unroll
      for (int k2 = 0; k2 < 8; ++k2) {
        const int slot = q * 8 + k2;
        const int tt = cbase + slot;
        if (tt >= 1) {
          const float v = op[slot * 64 + ss2] + op[slot * 64 + 16 + ss2] +
                          op[slot * 64 + 32 + ss2] + op[slot * 64 + 48 + ss2] + bl0;
          out[obase + tt - 1] = v;
        }
      }
      // no barrier needed: next OP write to these slots is after interval-1's
      // __syncthreads of step n+1.
    }
  }
}

extern "C" void kernel_launch(void* const* d_in, const int* in_sizes, int n_in,
                              void* d_out, int out_size, void* d_ws, size_t ws_size,
                              hipStream_t stream) {
  const float* y    = (const float*)d_in[0];
  const float* Wih1 = (const float*)d_in[1];
  const float* Whh1 = (const float*)d_in[2];
  const float* bih1 = (const float*)d_in[3];
  const float* bhh1 = (const float*)d_in[4];
  const float* Wih2 = (const float*)d_in[5];
  const float* Whh2 = (const float*)d_in[6];
  const float* bih2 = (const float*)d_in[7];
  const float* bhh2 = (const float*)d_in[8];
  const float* Wlin = (const float*)d_in[9];
  const float* blin = (const float*)d_in[10];
  float* out = (float*)d_out;

  hipFuncSetAttribute((const void*)lstm2_mfma,
                      hipFuncAttributeMaxDynamicSharedMemorySize, LDS_BYTES);
  lstm2_mfma<<<dim3(64), dim3(256), LDS_BYTES, stream>>>(
      y, Wih1, Whh1, bih1, bhh1, Wih2, Whh2, bih2, bhh2, Wlin, blin, out);
}

// Round 6
// 648.004 us; speedup vs baseline: 2.2450x; 2.2450x over previous
//
#include <hip/hip_runtime.h>

// 2-layer LSTM (H=64, D=1), N=2048, T=512 — MFMA bf16 3-term split precision.
// R6: layer-pipelined wave specialization. 128 blocks x 512 threads (8 waves,
// 2/SIMD). Waves 0-3 ("E") compute L1(k); waves 4-7 ("O") compute L2(k-1),
// one step behind. Per SIMD: one E + one O wave with independent schedules
// -> mutual stall covering. ONE barrier per iteration. h1/h2 planes
// double-buffered by step parity. Output partials buffered in a 128-slot LDS
// ring, flushed every 64 steps. Weights (hi+lo) register-resident per branch.

typedef __attribute__((ext_vector_type(8))) short short8;
typedef __attribute__((ext_vector_type(4))) float f32x4;

#define XPITCH 2060              // bytes (515 words, odd) -> conflict-free
#define XP 0                     // 16 * 2060 = 32960
#define HP 32960                 // 8 planes * 2304 = 18432
#define OPR 51392                // 128 slots * 4 ow * 16 s * 4 = 32768
#define LDS_BYTES 84160
// plane(layer, buf, hilo): 2304 B = [16 s][144 B], h[k] of sample s at byte s*144+2k
#define PLANE(layer, buf, hl) (HP + ((((layer) * 2 + (buf)) * 2) + (hl)) * 2304)

__device__ __forceinline__ float fast_rcp(float x) { return __builtin_amdgcn_rcpf(x); }
__device__ __forceinline__ float sigm(float x) { return fast_rcp(1.0f + __expf(-x)); }
__device__ __forceinline__ float tanh2(float x) {
  const float e = __expf(-2.0f * x);
  return fmaf(2.0f, fast_rcp(1.0f + e), -1.0f);
}
__device__ __forceinline__ unsigned short bf_rne(float f) {
  unsigned u = __float_as_uint(f);
  return (unsigned short)((u + 0x7FFFu + ((u >> 16) & 1u)) >> 16);
}
__device__ __forceinline__ void split8(const float* p, short8& hi, short8& lo) {
#pragma unroll
  for (int e = 0; e < 8; ++e) {
    float v = p[e];
    unsigned short h = bf_rne(v);
    float hf = __uint_as_float(((unsigned)h) << 16);
    hi[e] = (short)h;
    lo[e] = (short)bf_rne(v - hf);
  }
}
__device__ __forceinline__ unsigned cvt_pk(float a, float b) {
  unsigned r;
  asm("v_cvt_pk_bf16_f32 %0, %1, %2" : "=v"(r) : "v"(a), "v"(b));
  return r;
}
__device__ __forceinline__ f32x4 mfma16(short8 a, short8 b, f32x4 c) {
  return __builtin_amdgcn_mfma_f32_16x16x32_bf16(a, b, c, 0, 0, 0);
}

__global__ __launch_bounds__(512, 2) void lstm2_pipe(
    const float* __restrict__ y, const float* __restrict__ Wih1,
    const float* __restrict__ Whh1, const float* __restrict__ bih1,
    const float* __restrict__ bhh1, const float* __restrict__ Wih2,
    const float* __restrict__ Whh2, const float* __restrict__ bih2,
    const float* __restrict__ bhh2, const float* __restrict__ Wlin,
    const float* __restrict__ blin, float* __restrict__ out) {
  extern __shared__ char smem[];
  const int tid = threadIdx.x;
  const int w = tid >> 6;          // wave 0..7
  const int lane = tid & 63;
  const int g = lane >> 4;         // k-group 0..3
  const int s = lane & 15;         // sample col AND A row-within-tile
  const int s0 = blockIdx.x * 16;

  // ---- stage x: XP[ss][t] ----
  for (int i = tid; i < 16 * 512; i += 512) {
    const int ss = i >> 9, t = i & 511;
    *(float*)(smem + XP + ss * XPITCH + t * 4) = y[(size_t)(s0 + ss) * 512 + t];
  }
  // ---- zero all 8 h planes ----
  for (int i = tid; i < 18432 / 4; i += 512) *(float*)(smem + HP + i * 4) = 0.f;

  const float bl0 = blin[0];
  __syncthreads();

  if (w < 4) {
    // =================== E waves: layer 1, step k ===================
    short8 a1h[4][2], a1l[4][2];
    {
      const int row = 16 * w + s;
#pragma unroll
      for (int p = 0; p < 4; ++p)
#pragma unroll
        for (int c = 0; c < 2; ++c)
          split8(Whh1 + (size_t)(p * 64 + row) * 64 + 32 * c + 8 * g, a1h[p][c], a1l[p][c]);
    }
    float bias1c[4][4], wih1c[4][4];
#pragma unroll
    for (int p = 0; p < 4; ++p)
#pragma unroll
      for (int r = 0; r < 4; ++r) {
        const int row = p * 64 + 16 * w + 4 * g + r;
        bias1c[p][r] = bih1[row] + bhh1[row];
        wih1c[p][r] = Wih1[row];
      }
    float c1[4] = {0.f, 0.f, 0.f, 0.f};
    const int boffc0 = s * 144 + 16 * g;
    const int hoff = s * 144 + 32 * w + 8 * g;

#pragma unroll 1
    for (int k = 0; k <= 512; ++k) {
      if (k < 512) {
        const int rbuf = (k - 1) & 1;    // h1(k-1)
        const int wbuf = k & 1;          // h1(k)
        const float x = *(const float*)(smem + XP + s * XPITCH + k * 4);
        f32x4 acc[4];
#pragma unroll
        for (int p = 0; p < 4; ++p)
#pragma unroll
          for (int r = 0; r < 4; ++r) acc[p][r] = fmaf(wih1c[p][r], x, bias1c[p][r]);
#pragma unroll
        for (int c = 0; c < 2; ++c) {
          const int boff = boffc0 + 64 * c;
          const short8 Bh = *(const short8*)(smem + PLANE(0, rbuf, 0) + boff);
          const short8 Bl = *(const short8*)(smem + PLANE(0, rbuf, 1) + boff);
#pragma unroll
          for (int p = 0; p < 4; ++p) acc[p] = mfma16(a1h[p][c], Bh, acc[p]);
#pragma unroll
          for (int p = 0; p < 4; ++p) acc[p] = mfma16(a1h[p][c], Bl, acc[p]);
#pragma unroll
          for (int p = 0; p < 4; ++p) acc[p] = mfma16(a1l[p][c], Bh, acc[p]);
        }
        float h1n[4];
#pragma unroll
        for (int r = 0; r < 4; ++r) {
          const float ig = sigm(acc[0][r]), fg = sigm(acc[1][r]);
          const float gg = tanh2(acc[2][r]), og = sigm(acc[3][r]);
          c1[r] = fmaf(fg, c1[r], ig * gg);
          h1n[r] = og * tanh2(c1[r]);
        }
        const unsigned hA = cvt_pk(h1n[0], h1n[1]), hB = cvt_pk(h1n[2], h1n[3]);
        const unsigned lA = cvt_pk(h1n[0] - __uint_as_float(hA << 16),
                                   h1n[1] - __uint_as_float(hA & 0xFFFF0000u));
        const unsigned lB = cvt_pk(h1n[2] - __uint_as_float(hB << 16),
                                   h1n[3] - __uint_as_float(hB & 0xFFFF0000u));
        *(uint2*)(smem + PLANE(0, wbuf, 0) + hoff) = make_uint2(hA, hB);
        *(uint2*)(smem + PLANE(0, wbuf, 1) + hoff) = make_uint2(lA, lB);
      }
      __syncthreads();
    }
  } else {
    // =================== O waves: layer 2, step k-1 ===================
    const int ow = w - 4;
    short8 a2h[4][4], a2l[4][4];
    {
      const int row = 16 * ow + s;
#pragma unroll
      for (int p = 0; p < 4; ++p)
#pragma unroll
        for (int c = 0; c < 4; ++c) {
          const float* src = (c < 2) ? (Wih2 + (size_t)(p * 64 + row) * 64 + 32 * c + 8 * g)
                                     : (Whh2 + (size_t)(p * 64 + row) * 64 + 32 * (c - 2) + 8 * g);
          split8(src, a2h[p][c], a2l[p][c]);
        }
    }
    float bias2c[4][4], wlinc[4];
#pragma unroll
    for (int p = 0; p < 4; ++p)
#pragma unroll
      for (int r = 0; r < 4; ++r) {
        const int row = p * 64 + 16 * ow + 4 * g + r;
        bias2c[p][r] = bih2[row] + bhh2[row];
      }
#pragma unroll
    for (int r = 0; r < 4; ++r) wlinc[r] = Wlin[16 * ow + 4 * g + r];
    float c2[4] = {0.f, 0.f, 0.f, 0.f};
    const int boffc0 = s * 144 + 16 * g;
    const int hoff = s * 144 + 32 * ow + 8 * g;

#pragma unroll 1
    for (int k = 0; k <= 512; ++k) {
      // ---- flush a completed 64-slot half of the out ring (synced last barrier) ----
      if (k >= 66 && ((k - 2) & 63) == 0) {
        const int base = k - 66;
        const int thr = ow * 64 + lane;          // 0..255
        const int ss = thr & 15, grp = thr >> 4; // 16 groups x 4 slots
#pragma unroll
        for (int q = 0; q < 4; ++q) {
          const int idx = base + grp * 4 + q;
          const int slot = idx & 127;
          const char* op = smem + OPR + slot * 256 + ss * 4;
          const float v = *(const float*)(op) + *(const float*)(op + 64) +
                          *(const float*)(op + 128) + *(const float*)(op + 192) + bl0;
          out[(size_t)(s0 + ss) * 511 + idx] = v;
        }
      }
      if (k >= 1) {
        const int t2 = k - 1;                    // computing h2(t2)
        const int h1buf = (k - 1) & 1;           // h1(k-1) (written by E last iter)
        const int h2rbuf = k & 1;                // h2(k-2)
        const int h2wbuf = (k - 1) & 1;          // h2(k-1)
        f32x4 acc[4];
#pragma unroll
        for (int p = 0; p < 4; ++p)
#pragma unroll
          for (int r = 0; r < 4; ++r) acc[p][r] = bias2c[p][r];
#pragma unroll
        for (int c = 0; c < 4; ++c) {
          const int lay = (c < 2) ? 0 : 1;
          const int buf = (c < 2) ? h1buf : h2rbuf;
          const int boff = boffc0 + 64 * (c & 1);
          const short8 Bh = *(const short8*)(smem + PLANE(lay, buf, 0) + boff);
          const short8 Bl = *(const short8*)(smem + PLANE(lay, buf, 1) + boff);
#pragma unroll
          for (int p = 0; p < 4; ++p) acc[p] = mfma16(a2h[p][c], Bh, acc[p]);
#pragma unroll
          for (int p = 0; p < 4; ++p) acc[p] = mfma16(a2h[p][c], Bl, acc[p]);
#pragma unroll
          for (int p = 0; p < 4; ++p) acc[p] = mfma16(a2l[p][c], Bh, acc[p]);
        }
        float h2n[4];
#pragma unroll
        for (int r = 0; r < 4; ++r) {
          const float ig = sigm(acc[0][r]), fg = sigm(acc[1][r]);
          const float gg = tanh2(acc[2][r]), og = sigm(acc[3][r]);
          c2[r] = fmaf(fg, c2[r], ig * gg);
          h2n[r] = og * tanh2(c2[r]);
        }
        const unsigned hA = cvt_pk(h2n[0], h2n[1]), hB = cvt_pk(h2n[2], h2n[3]);
        const unsigned lA = cvt_pk(h2n[0] - __uint_as_float(hA << 16),
                                   h2n[1] - __uint_as_float(hA & 0xFFFF0000u));
        const unsigned lB = cvt_pk(h2n[2] - __uint_as_float(hB << 16),
                                   h2n[3] - __uint_as_float(hB & 0xFFFF0000u));
        *(uint2*)(smem + PLANE(1, h2wbuf, 0) + hoff) = make_uint2(hA, hB);
        *(uint2*)(smem + PLANE(1, h2wbuf, 1) + hoff) = make_uint2(lA, lB);

        // out(t2-1) partial: this wave's 16 rows reduced over g
        if (t2 >= 1) {
          float pw = wlinc[0] * h2n[0];
          pw = fmaf(wlinc[1], h2n[1], pw);
          pw = fmaf(wlinc[2], h2n[2], pw);
          pw = fmaf(wlinc[3], h2n[3], pw);
          pw += __shfl_xor(pw, 16, 64);
          pw += __shfl_xor(pw, 32, 64);
          if (g == 0)
            *(float*)(smem + OPR + ((t2 - 1) & 127) * 256 + ow * 64 + s * 4) = pw;
        }
      }
      __syncthreads();
    }
    // ---- tail flush: out idx 448..510 (written iters 450..512, synced) ----
    {
      const int thr = ow * 64 + lane;  // 0..255
      for (int e = thr; e < 63 * 16; e += 256) {
        const int ss = e & 15, off = e >> 4;   // off 0..62
        const int idx = 448 + off;
        const int slot = idx & 127;
        const char* op = smem + OPR + slot * 256 + ss * 4;
        const float v = *(const float*)(op) + *(const float*)(op + 64) +
                        *(const float*)(op + 128) + *(const float*)(op + 192) + bl0;
        out[(size_t)(s0 + ss) * 511 + idx] = v;
      }
    }
  }
}

extern "C" void kernel_launch(void* const* d_in, const int* in_sizes, int n_in,
                              void* d_out, int out_size, void* d_ws, size_t ws_size,
                              hipStream_t stream) {
  const float* y    = (const float*)d_in[0];
  const float* Wih1 = (const float*)d_in[1];
  const float* Whh1 = (const float*)d_in[2];
  const float* bih1 = (const float*)d_in[3];
  const float* bhh1 = (const float*)d_in[4];
  const float* Wih2 = (const float*)d_in[5];
  const float* Whh2 = (const float*)d_in[6];
  const float* bih2 = (const float*)d_in[7];
  const float* bhh2 = (const float*)d_in[8];
  const float* Wlin = (const float*)d_in[9];
  const float* blin = (const float*)d_in[10];
  float* out = (float*)d_out;

  hipFuncSetAttribute((const void*)lstm2_pipe,
                      hipFuncAttributeMaxDynamicSharedMemorySize, LDS_BYTES);
  lstm2_pipe<<<dim3(128), dim3(512), LDS_BYTES, stream>>>(
      y, Wih1, Whh1, bih1, bhh1, Wih2, Whh2, bih2, bhh2, Wlin, blin, out);
}